// Round 2
// baseline (498.092 us; speedup 1.0000x reference)
//
#include <hip/hip_runtime.h>

namespace {

constexpr float ALPHA = 0.2f;
constexpr float TAU   = 0.25f;
constexpr int   NITER = 10;
constexpr float EPSV  = 1e-12f;

constexpr int H = 256, W = 256;
constexpr int TILE = 64;
constexpr int HALO = 10;             // = NITER dependency radius
constexpr int RG   = TILE + 2*HALO;  // 84 region rows/cols
constexpr int QR   = RG / 4;         // 21 quads per region row
constexpr int NP   = RG / 2;         // 42 row pairs
constexpr int NTH  = NP * QR;        // 882 active threads
constexpr int NT   = 896;            // launched threads (14 waves)

// LDS: su full [84][84] | spx last-elem-per-quad [84][21] | spy odd rows [42][84]
// Order matters: all stray halo reads (spx[-1], spy[p-1], su overflow) land
// inside this block on bounded floats; they only affect region edge cells whose
// garbage propagates <=1 cell/iter and never reaches the 10..73 center tile.
constexpr int SU_OFF  = 0;
constexpr int SPX_OFF = RG * RG;            // 7056
constexpr int SPY_OFF = RG * RG + RG * QR;  // 8820
constexpr int LDS_FLOATS = RG*RG + RG*QR + NP*RG;  // 12348 floats = 49392 B

#if defined(__has_builtin)
#if __has_builtin(__builtin_amdgcn_rsqf)
#define RSQ(x) __builtin_amdgcn_rsqf(x)
#endif
#endif
#ifndef RSQ
#define RSQ(x) rsqrtf(x)
#endif

__launch_bounds__(NT, 7)
__global__ void tv_lrelu_kernel(const float* __restrict__ z,
                                const float* __restrict__ lam_p,
                                float* __restrict__ out) {
  __shared__ __align__(16) float lds[LDS_FLOATS];
  float* const su  = lds + SU_OFF;
  float* const spx = lds + SPX_OFF;
  float* const spy = lds + SPY_OFF;

  const float lam_c = fminf(fmaxf(lam_p[0], 0.0f), 1.0f);
  const float cg = lam_c * TAU;

  const int b   = blockIdx.x;
  const int img = b >> 4;
  const int tr  = (b >> 2) & 3;
  const int tc  = b & 3;
  const long base = (long)img * (H * W);
  const int r0 = tr * TILE - HALO;
  const int c0 = tc * TILE - HALO;

  const int tid = threadIdx.x;
  const bool act = tid < NTH;
  const int tw = act ? tid : 0;       // inactive lanes alias task 0 (reads only)
  const int p  = tw / QR;             // row pair index
  const int qc = tw - p * QR;         // quad column
  const int r  = 2 * p;               // upper (even) region row; lower = r+1
  const int gi0 = r0 + r, gi1 = gi0 + 1;
  const int gj  = c0 + qc * 4;

  // Boundary masks folded into coefficients (computed once).
  float cgx[4], mdx[4];
#pragma unroll
  for (int k = 0; k < 4; ++k) {
    cgx[k] = (gj + k < W - 1) ? cg : 0.0f;   // gx zeroed at last col
    mdx[k] = (gj + k > 0) ? 1.0f : 0.0f;     // div_x drops left term at col 0
  }
  const float cgy0 = (gi0 < H - 1) ? cg : 0.0f;
  const float cgy1 = (gi1 < H - 1) ? cg : 0.0f;
  const float mdy0 = (gi0 > 0) ? 1.0f : 0.0f;
  const float mdy1 = (gi1 > 0) ? 1.0f : 0.0f;

  // Per-thread state: 2 rows x 4 cols, all in registers.
  float z0[4], z1[4], u0[4], u1[4];
  float px0[4] = {0,0,0,0}, px1[4] = {0,0,0,0};
  float py0[4] = {0,0,0,0}, py1[4] = {0,0,0,0};

  {
    const bool rin0 = (gi0 >= 0) & (gi0 < H);
    const bool rin1 = (gi1 >= 0) & (gi1 < H);
    const float* zp0 = z + base + (long)gi0 * W + gj;
    const float* zp1 = z + base + (long)gi1 * W + gj;
#pragma unroll
    for (int k = 0; k < 4; ++k) {
      const bool cin = (gj + k >= 0) & (gj + k < W);
      z0[k] = (rin0 & cin) ? zp0[k] : 0.0f;
      z1[k] = (rin1 & cin) ? zp1[k] : 0.0f;
      u0[k] = fmaxf(z0[k], ALPHA * z0[k]);
      u1[k] = fmaxf(z1[k], ALPHA * z1[k]);
    }
  }

  // LDS element offsets (loop-invariant; +RG/+QR offsets fold to immediates).
  const int suw  = r * RG + qc * 4;   // su upper-row quad; lower at +RG
  const int spxw = r * QR + qc;       // spx upper; lower at +QR
  const int spyw = p * RG + qc * 4;   // spy slot of own lower (odd) row

  if (act) {
    *reinterpret_cast<float4*>(&su[suw])      = make_float4(u0[0],u0[1],u0[2],u0[3]);
    *reinterpret_cast<float4*>(&su[suw + RG]) = make_float4(u1[0],u1[1],u1[2],u1[3]);
  }
  __syncthreads();

  for (int t = 0; t < NITER; ++t) {
    // ---- phase 1: p += cg*grad(u), project ----
    const float4 udn  = *reinterpret_cast<const float4*>(&su[suw + 2*RG]); // u(r+2)
    const float  urt0 = su[suw + 4];        // u(r,   right quad elem 0)
    const float  urt1 = su[suw + RG + 4];   // u(r+1, right quad elem 0)

    const float un0[4] = {u0[1], u0[2], u0[3], urt0};
    const float un1[4] = {u1[1], u1[2], u1[3], urt1};
    const float ud1[4] = {udn.x, udn.y, udn.z, udn.w};
#pragma unroll
    for (int k = 0; k < 4; ++k) {           // upper row: u-down = own lower row
      px0[k] = fmaf(cgx[k], un0[k] - u0[k], px0[k]);
      py0[k] = fmaf(cgy0,   u1[k]  - u0[k], py0[k]);
      const float n2 = fmaf(px0[k], px0[k], fmaf(py0[k], py0[k], EPSV));
      const float sc = fminf(RSQ(n2), 1.0f);
      px0[k] *= sc; py0[k] *= sc;
    }
#pragma unroll
    for (int k = 0; k < 4; ++k) {           // lower row: u-down from LDS
      px1[k] = fmaf(cgx[k], un1[k] - u1[k], px1[k]);
      py1[k] = fmaf(cgy1,   ud1[k] - u1[k], py1[k]);
      const float n2 = fmaf(px1[k], px1[k], fmaf(py1[k], py1[k], EPSV));
      const float sc = fminf(RSQ(n2), 1.0f);
      px1[k] *= sc; py1[k] *= sc;
    }
    if (act) {
      spx[spxw]      = px0[3];
      spx[spxw + QR] = px1[3];
      *reinterpret_cast<float4*>(&spy[spyw]) = make_float4(py1[0],py1[1],py1[2],py1[3]);
    }
    __syncthreads();

    // ---- phase 2: u = lrelu(z + lam*div(p)) ----
    const float4 pyu4 = *reinterpret_cast<const float4*>(&spy[spyw - RG]); // py(r-1)
    const float  pxl0 = spx[spxw - 1];
    const float  pxl1 = spx[spxw + QR - 1];

    const float pxl0a[4] = {pxl0, px0[0], px0[1], px0[2]};
    const float pxl1a[4] = {pxl1, px1[0], px1[1], px1[2]};
    const float pyu0[4]  = {pyu4.x, pyu4.y, pyu4.z, pyu4.w};
#pragma unroll
    for (int k = 0; k < 4; ++k) {           // upper row: py-up from LDS
      const float d = (px0[k] - pxl0a[k]*mdx[k]) + (py0[k] - pyu0[k]*mdy0);
      const float a = fmaf(lam_c, d, z0[k]);
      u0[k] = fmaxf(a, ALPHA * a);
    }
#pragma unroll
    for (int k = 0; k < 4; ++k) {           // lower row: py-up = own upper row
      const float d = (px1[k] - pxl1a[k]*mdx[k]) + (py1[k] - py0[k]*mdy1);
      const float a = fmaf(lam_c, d, z1[k]);
      u1[k] = fmaxf(a, ALPHA * a);
    }
    if (act) {
      *reinterpret_cast<float4*>(&su[suw])      = make_float4(u0[0],u0[1],u0[2],u0[3]);
      *reinterpret_cast<float4*>(&su[suw + RG]) = make_float4(u1[0],u1[1],u1[2],u1[3]);
    }
    __syncthreads();
  }

  // ---- write center 64x64 tile from su ----
  const long obase = base + (long)(tr * TILE) * W + tc * TILE;
  for (int o = tid; o < TILE * 16; o += NT) {
    const int orow = o >> 4;
    const int oc   = o & 15;
    const float* srcp = &su[(HALO + orow) * RG + HALO + oc * 4];
    const float4 v = make_float4(srcp[0], srcp[1], srcp[2], srcp[3]);
    *reinterpret_cast<float4*>(out + obase + (long)orow * W + oc * 4) = v;
  }
}

} // namespace

extern "C" void kernel_launch(void* const* d_in, const int* in_sizes, int n_in,
                              void* d_out, int out_size, void* d_ws, size_t ws_size,
                              hipStream_t stream) {
  const float* z   = (const float*)d_in[0];
  const float* lam = (const float*)d_in[1];
  float* out = (float*)d_out;

  const int n_img = in_sizes[0] / (H * W);    // 512 for (8,64,256,256)
  const int n_blocks = n_img * 16;            // 4x4 tiles per image

  tv_lrelu_kernel<<<n_blocks, NT, 0, stream>>>(z, lam, out);
}

// Round 3
// 444.625 us; speedup vs baseline: 1.1203x; 1.1203x over previous
//
#include <hip/hip_runtime.h>

namespace {

constexpr float ALPHA = 0.2f;
constexpr float TAU   = 0.25f;
constexpr int   NITER = 10;
constexpr float EPSV  = 1e-12f;

constexpr int H = 256, W = 256;
constexpr int TILE = 64;
constexpr int HALO = 10;             // = NITER dependency radius
constexpr int RG   = TILE + 2*HALO;  // 84 region rows/cols
constexpr int QR   = RG / 4;         // 21 quads per region row
constexpr int NP   = RG / 2;         // 42 row pairs
constexpr int NTH  = NP * QR;        // 882 active threads
constexpr int NT   = 896;            // launched threads (14 waves)

// LDS: su full [84][84] | spx last-elem-per-quad [84][21] | spy odd rows [42][84]
// Order matters: all stray halo reads (spx[-1], spy[p-1], su overflow) land
// inside this block on bounded floats; they only affect region edge cells whose
// garbage propagates <=1 cell/iter and never reaches the 10..73 center tile.
constexpr int SU_OFF  = 0;
constexpr int SPX_OFF = RG * RG;            // 7056
constexpr int SPY_OFF = RG * RG + RG * QR;  // 8820
constexpr int LDS_FLOATS = RG*RG + RG*QR + NP*RG;  // 12348 floats = 49392 B
// 49392 B -> 2 blocks/CU = 99 KB < 160 KB. NO min-waves launch-bound hint:
// round 2's (NT,7) made the allocator spill (VGPR 36 + scratch writes to HBM)
// and capped residency at 1 block/CU.

#if defined(__has_builtin)
#if __has_builtin(__builtin_amdgcn_rsqf)
#define RSQ(x) __builtin_amdgcn_rsqf(x)
#endif
#endif
#ifndef RSQ
#define RSQ(x) rsqrtf(x)
#endif

__launch_bounds__(NT)
__global__ void tv_lrelu_kernel(const float* __restrict__ z,
                                const float* __restrict__ lam_p,
                                float* __restrict__ out) {
  __shared__ __align__(16) float lds[LDS_FLOATS];
  float* const su  = lds + SU_OFF;
  float* const spx = lds + SPX_OFF;
  float* const spy = lds + SPY_OFF;

  const float lam_c = fminf(fmaxf(lam_p[0], 0.0f), 1.0f);
  const float cg = lam_c * TAU;

  const int b   = blockIdx.x;
  const int img = b >> 4;
  const int tr  = (b >> 2) & 3;
  const int tc  = b & 3;
  const long base = (long)img * (H * W);
  const int r0 = tr * TILE - HALO;
  const int c0 = tc * TILE - HALO;

  const int tid = threadIdx.x;
  const bool act = tid < NTH;
  const int tw = act ? tid : 0;       // inactive lanes alias task 0 (reads only)
  const int p  = tw / QR;             // row pair index
  const int qc = tw - p * QR;         // quad column
  const int r  = 2 * p;               // upper (even) region row; lower = r+1
  const int gi0 = r0 + r, gi1 = gi0 + 1;
  const int gj  = c0 + qc * 4;

  // Boundary masks folded into coefficients (computed once).
  float cgx[4], mdx[4];
#pragma unroll
  for (int k = 0; k < 4; ++k) {
    cgx[k] = (gj + k < W - 1) ? cg : 0.0f;   // gx zeroed at last col
    mdx[k] = (gj + k > 0) ? 1.0f : 0.0f;     // div_x drops left term at col 0
  }
  const float cgy0 = (gi0 < H - 1) ? cg : 0.0f;
  const float cgy1 = (gi1 < H - 1) ? cg : 0.0f;
  const float mdy0 = (gi0 > 0) ? 1.0f : 0.0f;
  const float mdy1 = (gi1 > 0) ? 1.0f : 0.0f;

  // Per-thread state: 2 rows x 4 cols, all in registers.
  float z0[4], z1[4], u0[4], u1[4];
  float px0[4] = {0,0,0,0}, px1[4] = {0,0,0,0};
  float py0[4] = {0,0,0,0}, py1[4] = {0,0,0,0};

  {
    const bool rin0 = (gi0 >= 0) & (gi0 < H);
    const bool rin1 = (gi1 >= 0) & (gi1 < H);
    const float* zp0 = z + base + (long)gi0 * W + gj;
    const float* zp1 = z + base + (long)gi1 * W + gj;
#pragma unroll
    for (int k = 0; k < 4; ++k) {
      const bool cin = (gj + k >= 0) & (gj + k < W);
      z0[k] = (rin0 & cin) ? zp0[k] : 0.0f;
      z1[k] = (rin1 & cin) ? zp1[k] : 0.0f;
      u0[k] = fmaxf(z0[k], ALPHA * z0[k]);
      u1[k] = fmaxf(z1[k], ALPHA * z1[k]);
    }
  }

  // LDS element offsets (loop-invariant; +RG/+QR offsets fold to immediates).
  const int suw  = r * RG + qc * 4;   // su upper-row quad; lower at +RG
  const int spxw = r * QR + qc;       // spx upper; lower at +QR
  const int spyw = p * RG + qc * 4;   // spy slot of own lower (odd) row

  if (act) {
    *reinterpret_cast<float4*>(&su[suw])      = make_float4(u0[0],u0[1],u0[2],u0[3]);
    *reinterpret_cast<float4*>(&su[suw + RG]) = make_float4(u1[0],u1[1],u1[2],u1[3]);
  }
  __syncthreads();

  for (int t = 0; t < NITER; ++t) {
    // ---- phase 1: p += cg*grad(u), project ----
    const float4 udn  = *reinterpret_cast<const float4*>(&su[suw + 2*RG]); // u(r+2)
    const float  urt0 = su[suw + 4];        // u(r,   right quad elem 0)
    const float  urt1 = su[suw + RG + 4];   // u(r+1, right quad elem 0)

    const float un0[4] = {u0[1], u0[2], u0[3], urt0};
    const float un1[4] = {u1[1], u1[2], u1[3], urt1};
    const float ud1[4] = {udn.x, udn.y, udn.z, udn.w};
#pragma unroll
    for (int k = 0; k < 4; ++k) {           // upper row: u-down = own lower row
      px0[k] = fmaf(cgx[k], un0[k] - u0[k], px0[k]);
      py0[k] = fmaf(cgy0,   u1[k]  - u0[k], py0[k]);
      const float n2 = fmaf(px0[k], px0[k], fmaf(py0[k], py0[k], EPSV));
      const float sc = fminf(RSQ(n2), 1.0f);
      px0[k] *= sc; py0[k] *= sc;
    }
#pragma unroll
    for (int k = 0; k < 4; ++k) {           // lower row: u-down from LDS
      px1[k] = fmaf(cgx[k], un1[k] - u1[k], px1[k]);
      py1[k] = fmaf(cgy1,   ud1[k] - u1[k], py1[k]);
      const float n2 = fmaf(px1[k], px1[k], fmaf(py1[k], py1[k], EPSV));
      const float sc = fminf(RSQ(n2), 1.0f);
      px1[k] *= sc; py1[k] *= sc;
    }
    if (act) {
      spx[spxw]      = px0[3];
      spx[spxw + QR] = px1[3];
      *reinterpret_cast<float4*>(&spy[spyw]) = make_float4(py1[0],py1[1],py1[2],py1[3]);
    }
    __syncthreads();

    // ---- phase 2: u = lrelu(z + lam*div(p)) ----
    const float4 pyu4 = *reinterpret_cast<const float4*>(&spy[spyw - RG]); // py(r-1)
    const float  pxl0 = spx[spxw - 1];
    const float  pxl1 = spx[spxw + QR - 1];

    const float pxl0a[4] = {pxl0, px0[0], px0[1], px0[2]};
    const float pxl1a[4] = {pxl1, px1[0], px1[1], px1[2]};
    const float pyu0[4]  = {pyu4.x, pyu4.y, pyu4.z, pyu4.w};
#pragma unroll
    for (int k = 0; k < 4; ++k) {           // upper row: py-up from LDS
      const float d = (px0[k] - pxl0a[k]*mdx[k]) + (py0[k] - pyu0[k]*mdy0);
      const float a = fmaf(lam_c, d, z0[k]);
      u0[k] = fmaxf(a, ALPHA * a);
    }
#pragma unroll
    for (int k = 0; k < 4; ++k) {           // lower row: py-up = own upper row
      const float d = (px1[k] - pxl1a[k]*mdx[k]) + (py1[k] - py0[k]*mdy1);
      const float a = fmaf(lam_c, d, z1[k]);
      u1[k] = fmaxf(a, ALPHA * a);
    }
    if (act) {
      *reinterpret_cast<float4*>(&su[suw])      = make_float4(u0[0],u0[1],u0[2],u0[3]);
      *reinterpret_cast<float4*>(&su[suw + RG]) = make_float4(u1[0],u1[1],u1[2],u1[3]);
    }
    __syncthreads();
  }

  // ---- write center 64x64 tile from su ----
  const long obase = base + (long)(tr * TILE) * W + tc * TILE;
  for (int o = tid; o < TILE * 16; o += NT) {
    const int orow = o >> 4;
    const int oc   = o & 15;
    const float* srcp = &su[(HALO + orow) * RG + HALO + oc * 4];
    const float4 v = make_float4(srcp[0], srcp[1], srcp[2], srcp[3]);
    *reinterpret_cast<float4*>(out + obase + (long)orow * W + oc * 4) = v;
  }
}

} // namespace

extern "C" void kernel_launch(void* const* d_in, const int* in_sizes, int n_in,
                              void* d_out, int out_size, void* d_ws, size_t ws_size,
                              hipStream_t stream) {
  const float* z   = (const float*)d_in[0];
  const float* lam = (const float*)d_in[1];
  float* out = (float*)d_out;

  const int n_img = in_sizes[0] / (H * W);    // 512 for (8,64,256,256)
  const int n_blocks = n_img * 16;            // 4x4 tiles per image

  tv_lrelu_kernel<<<n_blocks, NT, 0, stream>>>(z, lam, out);
}

// Round 4
// 306.147 us; speedup vs baseline: 1.6270x; 1.4523x over previous
//
#include <hip/hip_runtime.h>

namespace {

constexpr float ALPHA = 0.2f;
constexpr float TAU   = 0.25f;
constexpr int   NITER = 10;
constexpr float EPSV  = 1e-12f;

constexpr int H = 256, W = 256;
constexpr int TILE = 64;
constexpr int HALO = 10;             // = NITER dependency radius (Chebyshev)
constexpr int RG   = TILE + 2*HALO;  // 84 region rows/cols
constexpr int QR   = RG / 4;         // 21 quads per region row
constexpr int RQ   = RG / 4;         // 21 four-row groups
constexpr int NTH  = RQ * QR;        // 441 active threads
constexpr int NT   = 448;            // 7 waves/block (<=512: multi-WG/CU hypothesis)

// LDS, exploiting the 4-row-per-thread grouping (only inter-thread data stored):
//   su_r0[22][84] : u rows ==0 mod 4 (down-neighbor reads), +1 pad row
//   su_c0[84][22] : u elem-0-of-quad  (right-neighbor reads), +1 pad col
//   spy  [21][84] : py rows ==3 mod 4 (up-neighbor reads)
//   spx  [84][21] : px elem-3-of-quad (left-neighbor reads)
// Stray reads (spy[-1], spx[-1], pad row/col, uninit at t=0) stay inside this
// block, are bounded-or-NaN, corrupt only region edge cells, and edge garbage
// propagates 1 cell/iter -> reaches rows/cols <=9 or >=74, never 10..73 output.
constexpr int SUR0_OFF = 0;
constexpr int SUC0_OFF = 22 * RG;                    // 1848
constexpr int SPY_OFF  = SUC0_OFF + RG * 22;         // 3696
constexpr int SPX_OFF  = SPY_OFF + RQ * RG;          // 5460
constexpr int LDS_FLOATS = SPX_OFF + RG * QR;        // 7224 floats = 28896 B

#if defined(__has_builtin)
#if __has_builtin(__builtin_amdgcn_rsqf)
#define RSQ(x) __builtin_amdgcn_rsqf(x)
#endif
#endif
#ifndef RSQ
#define RSQ(x) rsqrtf(x)
#endif

__launch_bounds__(NT, 4)   // VGPR cap 128; state needs ~100 -> no spill expected
__global__ void tv_lrelu_kernel(const float* __restrict__ z,
                                const float* __restrict__ lam_p,
                                float* __restrict__ out) {
  __shared__ __align__(16) float lds[LDS_FLOATS];
  float* const su_r0 = lds + SUR0_OFF;
  float* const su_c0 = lds + SUC0_OFF;
  float* const spy   = lds + SPY_OFF;
  float* const spx   = lds + SPX_OFF;

  const float lam_c = fminf(fmaxf(lam_p[0], 0.0f), 1.0f);
  const float cg = lam_c * TAU;

  const int b   = blockIdx.x;
  const int img = b >> 4;
  const int tr  = (b >> 2) & 3;
  const int tc  = b & 3;
  const long base = (long)img * (H * W);
  const int r0 = tr * TILE - HALO;
  const int c0 = tc * TILE - HALO;

  const int tid = threadIdx.x;
  const bool act = tid < NTH;
  const int tw = act ? tid : 0;       // inactive lanes alias task 0 (reads only)
  const int rq = tw / QR;             // 4-row group index
  const int qc = tw - rq * QR;        // quad column
  const int r  = 4 * rq;              // top region row of this thread
  const int gj = c0 + qc * 4;

  // Boundary masks folded into coefficients (computed once).
  float cgx[4], mdx[4], cgy[4], mdy[4];
#pragma unroll
  for (int k = 0; k < 4; ++k) {
    cgx[k] = (gj + k < W - 1) ? cg : 0.0f;   // gx zeroed at last col
    mdx[k] = (gj + k > 0) ? 1.0f : 0.0f;     // div_x drops left term at col 0
  }
#pragma unroll
  for (int i = 0; i < 4; ++i) {
    const int gi = r0 + r + i;
    cgy[i] = (gi < H - 1) ? cg : 0.0f;
    mdy[i] = (gi > 0) ? 1.0f : 0.0f;
  }

  // Per-thread state: 4 rows x 4 cols, all in registers.
  float zq[4][4], u[4][4];
  float px[4][4] = {};
  float py[4][4] = {};

#pragma unroll
  for (int i = 0; i < 4; ++i) {
    const int gi = r0 + r + i;
    const bool rin = (gi >= 0) & (gi < H);
    const float* zp = z + base + (long)gi * W + gj;
#pragma unroll
    for (int k = 0; k < 4; ++k) {
      const bool cin = (gj + k >= 0) & (gj + k < W);
      const float zv = (rin & cin) ? zp[k] : 0.0f;
      zq[i][k] = zv;
      u[i][k]  = fmaxf(zv, ALPHA * zv);      // leaky_relu(z)
    }
  }

  // LDS element offsets (loop-invariant).
  const int sur0_w = rq * RG + qc * 4;       // su_r0[rq][4qc]      (b128)
  const int suc0_w = r * 22 + qc;            // su_c0[r+i][qc] = +i*22
  const int spy_w  = rq * RG + qc * 4;       // spy[rq][4qc]        (b128)
  const int spx_w  = r * QR + qc;            // spx[r+i][qc] = +i*21

  if (act) {
    *reinterpret_cast<float4*>(&su_r0[sur0_w]) =
        make_float4(u[0][0], u[0][1], u[0][2], u[0][3]);
#pragma unroll
    for (int i = 0; i < 4; ++i) su_c0[suc0_w + i * 22] = u[i][0];
  }
  __syncthreads();

  for (int t = 0; t < NITER; ++t) {
    // ---- phase 1: p += cg*grad(u), project onto unit ball ----
    const float4 udn = *reinterpret_cast<const float4*>(&su_r0[sur0_w + RG]);
    float ur[4];
#pragma unroll
    for (int i = 0; i < 4; ++i) ur[i] = su_c0[suc0_w + i * 22 + 1];
    const float dn[4] = {udn.x, udn.y, udn.z, udn.w};

#pragma unroll
    for (int i = 0; i < 4; ++i) {
      const float un[4] = {u[i][1], u[i][2], u[i][3], ur[i]};   // u(i, j+1)
#pragma unroll
      for (int k = 0; k < 4; ++k) {
        const float ud = (i < 3) ? u[(i + 1 < 4) ? i + 1 : 0][k] : dn[k];
        px[i][k] = fmaf(cgx[k], un[k] - u[i][k], px[i][k]);
        py[i][k] = fmaf(cgy[i], ud    - u[i][k], py[i][k]);
        const float n2 = fmaf(px[i][k], px[i][k], fmaf(py[i][k], py[i][k], EPSV));
        const float sc = fminf(RSQ(n2), 1.0f);
        px[i][k] *= sc;
        py[i][k] *= sc;
      }
    }
    if (act) {
#pragma unroll
      for (int i = 0; i < 4; ++i) spx[spx_w + i * QR] = px[i][3];
      *reinterpret_cast<float4*>(&spy[spy_w]) =
          make_float4(py[3][0], py[3][1], py[3][2], py[3][3]);
    }
    __syncthreads();

    // ---- phase 2: u = lrelu(z + lam*div(p)) ----
    const float4 pyu4 = *reinterpret_cast<const float4*>(&spy[spy_w - RG]);
    float pxl[4];
#pragma unroll
    for (int i = 0; i < 4; ++i) pxl[i] = spx[spx_w + i * QR - 1];
    const float up[4] = {pyu4.x, pyu4.y, pyu4.z, pyu4.w};

#pragma unroll
    for (int i = 0; i < 4; ++i) {
      const float pxs[4] = {pxl[i], px[i][0], px[i][1], px[i][2]};  // px(i, j-1)
#pragma unroll
      for (int k = 0; k < 4; ++k) {
        const float pyu = (i == 0) ? up[k] : py[(i > 0) ? i - 1 : 0][k];
        const float d = (px[i][k] - pxs[k] * mdx[k]) + (py[i][k] - pyu * mdy[i]);
        const float a = fmaf(lam_c, d, zq[i][k]);
        u[i][k] = fmaxf(a, ALPHA * a);
      }
    }
    if (act) {
      *reinterpret_cast<float4*>(&su_r0[sur0_w]) =
          make_float4(u[0][0], u[0][1], u[0][2], u[0][3]);
#pragma unroll
      for (int i = 0; i < 4; ++i) su_c0[suc0_w + i * 22] = u[i][0];
    }
    __syncthreads();
  }

  // ---- write center 64x64 tile straight from registers ----
  if (act) {
#pragma unroll
    for (int i = 0; i < 4; ++i) {
      const int rr = r + i;                       // region row
      if (rr >= HALO && rr < HALO + TILE) {
        float* dst = out + base + (long)(r0 + rr) * W + gj;
        if (qc >= 3 && qc <= 17) {                // quad fully inside cols 10..73
          *reinterpret_cast<float4*>(dst) =
              make_float4(u[i][0], u[i][1], u[i][2], u[i][3]);
        } else if (qc == 2 || qc == 18) {         // partial edge quads
#pragma unroll
          for (int k = 0; k < 4; ++k) {
            const int cc = qc * 4 + k;            // region col
            if (cc >= HALO && cc < HALO + TILE) dst[k] = u[i][k];
          }
        }
      }
    }
  }
}

} // namespace

extern "C" void kernel_launch(void* const* d_in, const int* in_sizes, int n_in,
                              void* d_out, int out_size, void* d_ws, size_t ws_size,
                              hipStream_t stream) {
  const float* z   = (const float*)d_in[0];
  const float* lam = (const float*)d_in[1];
  float* out = (float*)d_out;

  const int n_img = in_sizes[0] / (H * W);    // 512 for (8,64,256,256)
  const int n_blocks = n_img * 16;            // 4x4 tiles per image

  tv_lrelu_kernel<<<n_blocks, NT, 0, stream>>>(z, lam, out);
}

// Round 5
// 291.000 us; speedup vs baseline: 1.7117x; 1.0521x over previous
//
#include <hip/hip_runtime.h>

namespace {

constexpr float ALPHA = 0.2f;
constexpr float TAU   = 0.25f;
constexpr int   NITER = 10;
constexpr float EPSV  = 1e-12f;

constexpr int H = 256, W = 256;
constexpr int TILE = 64;
constexpr int HALO = 10;             // = NITER dependency radius (Chebyshev)
constexpr int RG   = TILE + 2*HALO;  // 84 region rows/cols
constexpr int QR   = RG / 4;         // 21 quads per region row
constexpr int RQ   = RG / 4;         // 21 four-row groups
constexpr int NTH  = RQ * QR;        // 441 active threads
constexpr int NT   = 448;            // 7 waves/block (<=512 keeps 2 blocks/CU resident)

// LDS, exploiting the 4-row-per-thread grouping (only inter-thread data stored):
//   su_r0[22][84] : u rows ==0 mod 4 (down-neighbor reads), +1 pad row
//   su_c0[84][22] : u elem-0-of-quad  (right-neighbor reads), +1 pad col
//   spy  [21][84] : py rows ==3 mod 4 (up-neighbor reads)
//   spx  [84][21] : px elem-3-of-quad (left-neighbor reads)
// Stray reads (spy[-1], spx[-1], pad row/col, uninit at t=0) stay inside this
// block, are bounded-or-NaN, corrupt only region edge cells, and edge garbage
// propagates 1 cell/iter -> reaches rows/cols <=9 or >=74, never 10..73 output.
constexpr int SUR0_OFF = 0;
constexpr int SUC0_OFF = 22 * RG;                    // 1848
constexpr int SPY_OFF  = SUC0_OFF + RG * 22;         // 3696
constexpr int SPX_OFF  = SPY_OFF + RQ * RG;          // 5460
constexpr int LDS_FLOATS = SPX_OFF + RG * QR;        // 7224 floats = 28896 B

typedef float v2f __attribute__((ext_vector_type(2)));

#if defined(__has_builtin)
#if __has_builtin(__builtin_amdgcn_rsqf)
#define RSQ(x) __builtin_amdgcn_rsqf(x)
#endif
#endif
#ifndef RSQ
#define RSQ(x) rsqrtf(x)
#endif

__launch_bounds__(NT, 4)   // VGPR cap 128; packed state ~100 -> no spill expected
__global__ void tv_lrelu_kernel(const float* __restrict__ z,
                                const float* __restrict__ lam_p,
                                float* __restrict__ out) {
  __shared__ __align__(16) float lds[LDS_FLOATS];
  float* const su_r0 = lds + SUR0_OFF;
  float* const su_c0 = lds + SUC0_OFF;
  float* const spy   = lds + SPY_OFF;
  float* const spx   = lds + SPX_OFF;

  const float lam_c = fminf(fmaxf(lam_p[0], 0.0f), 1.0f);
  const float cg = lam_c * TAU;
  const v2f lam2   = {lam_c, lam_c};
  const v2f alpha2 = {ALPHA, ALPHA};
  const v2f eps2   = {EPSV, EPSV};

  const int b   = blockIdx.x;
  const int img = b >> 4;
  const int tr  = (b >> 2) & 3;
  const int tc  = b & 3;
  const long base = (long)img * (H * W);
  const int r0 = tr * TILE - HALO;
  const int c0 = tc * TILE - HALO;

  const int tid = threadIdx.x;
  const bool act = tid < NTH;
  const int tw = act ? tid : 0;       // inactive lanes alias task 0 (reads only)
  const int rq = tw / QR;             // 4-row group index
  const int qc = tw - rq * QR;        // quad column
  const int r  = 4 * rq;              // top region row of this thread
  const int gj = c0 + qc * 4;

  // Boundary masks folded into packed coefficients (computed once).
  v2f cgx[2], mdx[2];
#pragma unroll
  for (int k = 0; k < 4; ++k) {
    reinterpret_cast<float*>(cgx)[k] = (gj + k < W - 1) ? cg : 0.0f; // gx=0 last col
    reinterpret_cast<float*>(mdx)[k] = (gj + k > 0) ? 1.0f : 0.0f;   // div_x col 0
  }
  float cgy[4], mdy[4];
#pragma unroll
  for (int i = 0; i < 4; ++i) {
    const int gi = r0 + r + i;
    cgy[i] = (gi < H - 1) ? cg : 0.0f;
    mdy[i] = (gi > 0) ? 1.0f : 0.0f;
  }

  // Per-thread state: 4 rows x 2 column-pairs, all in (paired) registers.
  v2f zq[4][2], u[4][2];
  v2f px[4][2] = {};
  v2f py[4][2] = {};

#pragma unroll
  for (int i = 0; i < 4; ++i) {
    const int gi = r0 + r + i;
    const bool rin = (gi >= 0) & (gi < H);
    const float* zp = z + base + (long)gi * W + gj;
    float zv[4];
#pragma unroll
    for (int k = 0; k < 4; ++k) {
      const bool cin = (gj + k >= 0) & (gj + k < W);
      zv[k] = (rin & cin) ? zp[k] : 0.0f;
    }
    zq[i][0] = (v2f){zv[0], zv[1]};
    zq[i][1] = (v2f){zv[2], zv[3]};
#pragma unroll
    for (int j = 0; j < 2; ++j) {
      const v2f a = zq[i][j] * alpha2;
      u[i][j] = (v2f){fmaxf(zq[i][j].x, a.x), fmaxf(zq[i][j].y, a.y)};
    }
  }

  // LDS element offsets (loop-invariant).
  const int sur0_w = rq * RG + qc * 4;       // su_r0[rq][4qc]      (b128)
  const int suc0_w = r * 22 + qc;            // su_c0[r+i][qc] = +i*22
  const int spy_w  = rq * RG + qc * 4;       // spy[rq][4qc]        (b128)
  const int spx_w  = r * QR + qc;            // spx[r+i][qc] = +i*21

  if (act) {
    *reinterpret_cast<float4*>(&su_r0[sur0_w]) =
        make_float4(u[0][0].x, u[0][0].y, u[0][1].x, u[0][1].y);
#pragma unroll
    for (int i = 0; i < 4; ++i) su_c0[suc0_w + i * 22] = u[i][0].x;
  }
  __syncthreads();

  for (int t = 0; t < NITER; ++t) {
    // ---- phase 1: p += cg*grad(u), project onto unit ball ----
    const float4 udn = *reinterpret_cast<const float4*>(&su_r0[sur0_w + RG]);
    float ur[4];
#pragma unroll
    for (int i = 0; i < 4; ++i) ur[i] = su_c0[suc0_w + i * 22 + 1];
    const v2f dn0 = {udn.x, udn.y}, dn1 = {udn.z, udn.w};

#pragma unroll
    for (int i = 0; i < 4; ++i) {
      const v2f un0 = {u[i][0].y, u[i][1].x};            // u(i, j+1)
      const v2f un1 = {u[i][1].y, ur[i]};
      const v2f ud0 = (i < 3) ? u[(i < 3) ? i + 1 : 0][0] : dn0;  // u(i+1, j)
      const v2f ud1 = (i < 3) ? u[(i < 3) ? i + 1 : 0][1] : dn1;
      const v2f cgys = {cgy[i], cgy[i]};

      px[i][0] = __builtin_elementwise_fma(cgx[0], un0 - u[i][0], px[i][0]);
      px[i][1] = __builtin_elementwise_fma(cgx[1], un1 - u[i][1], px[i][1]);
      py[i][0] = __builtin_elementwise_fma(cgys,   ud0 - u[i][0], py[i][0]);
      py[i][1] = __builtin_elementwise_fma(cgys,   ud1 - u[i][1], py[i][1]);
#pragma unroll
      for (int j = 0; j < 2; ++j) {
        const v2f n2 = __builtin_elementwise_fma(
            px[i][j], px[i][j],
            __builtin_elementwise_fma(py[i][j], py[i][j], eps2));
        const v2f sc = {fminf(RSQ(n2.x), 1.0f), fminf(RSQ(n2.y), 1.0f)};
        px[i][j] *= sc;
        py[i][j] *= sc;
      }
    }
    if (act) {
#pragma unroll
      for (int i = 0; i < 4; ++i) spx[spx_w + i * QR] = px[i][1].y;
      *reinterpret_cast<float4*>(&spy[spy_w]) =
          make_float4(py[3][0].x, py[3][0].y, py[3][1].x, py[3][1].y);
    }
    __syncthreads();

    // ---- phase 2: u = lrelu(z + lam*div(p)) ----
    const float4 pyu4 = *reinterpret_cast<const float4*>(&spy[spy_w - RG]);
    float pxl[4];
#pragma unroll
    for (int i = 0; i < 4; ++i) pxl[i] = spx[spx_w + i * QR - 1];
    const v2f up0 = {pyu4.x, pyu4.y}, up1 = {pyu4.z, pyu4.w};

#pragma unroll
    for (int i = 0; i < 4; ++i) {
      const v2f pxs0 = {pxl[i], px[i][0].x};             // px(i, j-1)
      const v2f pxs1 = {px[i][0].y, px[i][1].x};
      const v2f pyu0 = (i == 0) ? up0 : py[(i > 0) ? i - 1 : 0][0];  // py(i-1, j)
      const v2f pyu1 = (i == 0) ? up1 : py[(i > 0) ? i - 1 : 0][1];
      const v2f mdys = {mdy[i], mdy[i]};

      const v2f d0 = (px[i][0] - pxs0 * mdx[0]) + (py[i][0] - pyu0 * mdys);
      const v2f d1 = (px[i][1] - pxs1 * mdx[1]) + (py[i][1] - pyu1 * mdys);
      const v2f a0 = __builtin_elementwise_fma(lam2, d0, zq[i][0]);
      const v2f a1 = __builtin_elementwise_fma(lam2, d1, zq[i][1]);
      const v2f b0 = a0 * alpha2;
      const v2f b1 = a1 * alpha2;
      u[i][0] = (v2f){fmaxf(a0.x, b0.x), fmaxf(a0.y, b0.y)};
      u[i][1] = (v2f){fmaxf(a1.x, b1.x), fmaxf(a1.y, b1.y)};
    }
    if (act) {
      *reinterpret_cast<float4*>(&su_r0[sur0_w]) =
          make_float4(u[0][0].x, u[0][0].y, u[0][1].x, u[0][1].y);
#pragma unroll
      for (int i = 0; i < 4; ++i) su_c0[suc0_w + i * 22] = u[i][0].x;
    }
    __syncthreads();
  }

  // ---- write center 64x64 tile straight from registers ----
  if (act) {
#pragma unroll
    for (int i = 0; i < 4; ++i) {
      const int rr = r + i;                       // region row
      if (rr >= HALO && rr < HALO + TILE) {
        float* dst = out + base + (long)(r0 + rr) * W + gj;
        if (qc >= 3 && qc <= 17) {                // quad fully inside cols 10..73
          *reinterpret_cast<float4*>(dst) =
              make_float4(u[i][0].x, u[i][0].y, u[i][1].x, u[i][1].y);
        } else if (qc == 2 || qc == 18) {         // partial edge quads
          const float uv[4] = {u[i][0].x, u[i][0].y, u[i][1].x, u[i][1].y};
#pragma unroll
          for (int k = 0; k < 4; ++k) {
            const int cc = qc * 4 + k;            // region col
            if (cc >= HALO && cc < HALO + TILE) dst[k] = uv[k];
          }
        }
      }
    }
  }
}

} // namespace

extern "C" void kernel_launch(void* const* d_in, const int* in_sizes, int n_in,
                              void* d_out, int out_size, void* d_ws, size_t ws_size,
                              hipStream_t stream) {
  const float* z   = (const float*)d_in[0];
  const float* lam = (const float*)d_in[1];
  float* out = (float*)d_out;

  const int n_img = in_sizes[0] / (H * W);    // 512 for (8,64,256,256)
  const int n_blocks = n_img * 16;            // 4x4 tiles per image

  tv_lrelu_kernel<<<n_blocks, NT, 0, stream>>>(z, lam, out);
}

// Round 6
// 289.405 us; speedup vs baseline: 1.7211x; 1.0055x over previous
//
#include <hip/hip_runtime.h>

namespace {

constexpr float ALPHA = 0.2f;
constexpr float TAU   = 0.25f;
constexpr int   NITER = 10;

constexpr int H = 256, W = 256;
constexpr int TILE = 64;
constexpr int HALO = 10;             // = NITER dependency radius (Chebyshev)
constexpr int RG   = TILE + 2*HALO;  // 84 region rows/cols
constexpr int QR   = RG / 4;         // 21 quads per region row
constexpr int RQ   = RG / 4;         // 21 four-row groups
constexpr int NTH  = RQ * QR;        // 441 active threads
constexpr int NT   = 448;            // 7 waves (<=512 keeps 2 blocks/CU resident)

// LDS (inter-thread exchange only) + 96-float dump zone for the 7 pad lanes:
//   su_r0[22][84] : u rows ==0 mod 4 (down-neighbor reads)
//   su_c0[84][22] : u elem-0-of-quad (right-neighbor reads)
//   spy  [21][84] : py rows ==3 mod 4 (up-neighbor reads)
//   spx  [84][21] : px elem-3-of-quad (left-neighbor reads)
//   dump [96]     : pad lanes' unconditional loop stores land here
// Stray halo reads stay inside this block, are bounded, corrupt only region
// edge cells; edge garbage propagates 1 cell/iter -> reaches rows/cols <=9 or
// >=74, never the 10..73 output window.
constexpr int SUR0_OFF = 0;
constexpr int SUC0_OFF = 22 * RG;                    // 1848
constexpr int SPY_OFF  = SUC0_OFF + RG * 22;         // 3696
constexpr int SPX_OFF  = SPY_OFF + RQ * RG;          // 5460
constexpr int DUMP_OFF = SPX_OFF + RG * QR;          // 7224
constexpr int LDS_FLOATS = DUMP_OFF + 96;            // 7320 floats = 29280 B

// Per-array dump overrides (element offsets relative to each array base so the
// absolute address lands in [DUMP_OFF, DUMP_OFF+96) for every loop access):
constexpr int DUMP_SUR0 = DUMP_OFF - SUR0_OFF;           // reads +RG -> +84..87
constexpr int DUMP_SUC0 = DUMP_OFF - SUC0_OFF;           // +i*22(+1) -> 0..67
constexpr int DUMP_SPY  = DUMP_OFF - SPY_OFF + 84;       // read -RG -> +0..3
constexpr int DUMP_SPX  = DUMP_OFF - SPX_OFF + 1;        // read -1  -> +0..64

typedef float v2f __attribute__((ext_vector_type(2)));

#if defined(__has_builtin)
#if __has_builtin(__builtin_amdgcn_rsqf)
#define RSQ(x) __builtin_amdgcn_rsqf(x)
#endif
#endif
#ifndef RSQ
#define RSQ(x) rsqrtf(x)
#endif

__launch_bounds__(NT, 4)
__global__ void tv_lrelu_kernel(const float* __restrict__ z,
                                const float* __restrict__ lam_p,
                                float* __restrict__ out) {
  __shared__ __align__(16) float lds[LDS_FLOATS];
  float* const su_r0 = lds + SUR0_OFF;
  float* const su_c0 = lds + SUC0_OFF;
  float* const spy   = lds + SPY_OFF;
  float* const spx   = lds + SPX_OFF;

  const float lam_c = fminf(fmaxf(lam_p[0], 0.0f), 1.0f);
  const float cg = lam_c * TAU;

  const int b   = blockIdx.x;
  const int img = b >> 4;
  const int tr  = (b >> 2) & 3;
  const int tc  = b & 3;
  const long base = (long)img * (H * W);
  const int r0 = tr * TILE - HALO;
  const int c0 = tc * TILE - HALO;

  const int tid = threadIdx.x;
  const bool act = tid < NTH;
  const int tw = act ? tid : 0;       // pad lanes alias task 0 (global reads only)
  const int rq = tw / QR;             // 4-row group index
  const int qc = tw - rq * QR;        // quad column
  const int r  = 4 * rq;              // top region row of this thread
  const int gj = c0 + qc * 4;

  // Boundary masks folded into coefficients (computed once).
  v2f cgx[2], nlmdx[2];
#pragma unroll
  for (int k = 0; k < 4; ++k) {
    // gx zeroed at last image col; div_x drops left term at image col 0
    reinterpret_cast<float*>(cgx)[k]   = (gj + k < W - 1) ? cg : 0.0f;
    reinterpret_cast<float*>(nlmdx)[k] = (gj + k > 0) ? -lam_c : 0.0f;
  }
  float cgy[4], nlmy[4];
#pragma unroll
  for (int i = 0; i < 4; ++i) {
    const int gi = r0 + r + i;
    cgy[i]  = (gi < H - 1) ? cg : 0.0f;
    nlmy[i] = (gi > 0) ? -lam_c : 0.0f;
  }

  // Per-thread state: 4 rows x 2 column-pairs, all in (paired) registers.
  v2f zq[4][2], u[4][2];
  v2f px[4][2] = {};
  v2f py[4][2] = {};

#pragma unroll
  for (int i = 0; i < 4; ++i) {
    const int gi = r0 + r + i;
    const bool rin = (gi >= 0) & (gi < H);
    const float* zp = z + base + (long)gi * W + gj;
    float zv[4];
#pragma unroll
    for (int k = 0; k < 4; ++k) {
      const bool cin = (gj + k >= 0) & (gj + k < W);
      zv[k] = (rin & cin) ? zp[k] : 0.0f;
    }
    zq[i][0] = (v2f){zv[0], zv[1]};
    zq[i][1] = (v2f){zv[2], zv[3]};
#pragma unroll
    for (int j = 0; j < 2; ++j)
      u[i][j] = __builtin_elementwise_max(zq[i][j], zq[i][j] * ALPHA);
  }

  // LDS element offsets; pad lanes are redirected into the dump zone so all
  // loop-body LDS ops are unconditional (no exec-mask toggling in the loop).
  const int sur0_w = act ? (rq * RG + qc * 4) : DUMP_SUR0;
  const int suc0_w = act ? (r * 22 + qc)      : DUMP_SUC0;
  const int spy_w  = act ? (rq * RG + qc * 4) : DUMP_SPY;
  const int spx_w  = act ? (r * QR + qc)      : DUMP_SPX;

  *reinterpret_cast<float4*>(&su_r0[sur0_w]) =
      make_float4(u[0][0].x, u[0][0].y, u[0][1].x, u[0][1].y);
#pragma unroll
  for (int i = 0; i < 4; ++i) su_c0[suc0_w + i * 22] = u[i][0].x;
  __syncthreads();

  for (int t = 0; t < NITER; ++t) {
    // ---- phase 1: p += cg*grad(u), project onto unit ball ----
    const float4 udn = *reinterpret_cast<const float4*>(&su_r0[sur0_w + RG]);
    float ur[4];
#pragma unroll
    for (int i = 0; i < 4; ++i) ur[i] = su_c0[suc0_w + i * 22 + 1];
    const v2f dn0 = {udn.x, udn.y}, dn1 = {udn.z, udn.w};

#pragma unroll
    for (int i = 0; i < 4; ++i) {
      const v2f un0 = {u[i][0].y, u[i][1].x};            // u(i, j+1)
      const v2f un1 = {u[i][1].y, ur[i]};
      const v2f ud0 = (i < 3) ? u[(i < 3) ? i + 1 : 0][0] : dn0;  // u(i+1, j)
      const v2f ud1 = (i < 3) ? u[(i < 3) ? i + 1 : 0][1] : dn1;

      px[i][0] = __builtin_elementwise_fma(cgx[0], un0 - u[i][0], px[i][0]);
      px[i][1] = __builtin_elementwise_fma(cgx[1], un1 - u[i][1], px[i][1]);
      py[i][0] = __builtin_elementwise_fma((v2f)cgy[i], ud0 - u[i][0], py[i][0]);
      py[i][1] = __builtin_elementwise_fma((v2f)cgy[i], ud1 - u[i][1], py[i][1]);
#pragma unroll
      for (int j = 0; j < 2; ++j) {
        // 1/max(norm,1) == rsqrt(max(norm^2,1)); rsq(1.0)=1.0 exactly.
        const v2f n2 = __builtin_elementwise_fma(px[i][j], px[i][j],
                                                 py[i][j] * py[i][j]);
        const v2f m = __builtin_elementwise_max(n2, (v2f)1.0f);
        const v2f sc = {RSQ(m.x), RSQ(m.y)};
        px[i][j] *= sc;
        py[i][j] *= sc;
      }
    }
#pragma unroll
    for (int i = 0; i < 4; ++i) spx[spx_w + i * QR] = px[i][1].y;
    *reinterpret_cast<float4*>(&spy[spy_w]) =
        make_float4(py[3][0].x, py[3][0].y, py[3][1].x, py[3][1].y);
    __syncthreads();

    // ---- phase 2: u = lrelu(z + lam*div(p)) ----
    const float4 pyu4 = *reinterpret_cast<const float4*>(&spy[spy_w - RG]);
    float pxl[4];
#pragma unroll
    for (int i = 0; i < 4; ++i) pxl[i] = spx[spx_w + i * QR - 1];
    const v2f up0 = {pyu4.x, pyu4.y}, up1 = {pyu4.z, pyu4.w};

#pragma unroll
    for (int i = 0; i < 4; ++i) {
      const v2f pxs0 = {pxl[i], px[i][0].x};             // px(i, j-1)
      const v2f pxs1 = {px[i][0].y, px[i][1].x};
      const v2f pyu0 = (i == 0) ? up0 : py[(i > 0) ? i - 1 : 0][0];  // py(i-1, j)
      const v2f pyu1 = (i == 0) ? up1 : py[(i > 0) ? i - 1 : 0][1];

      // a = z + lam*(px+py) - (lam*mdx)*pxl - (lam*mdy)*pyu
      v2f a0 = __builtin_elementwise_fma((v2f)lam_c, px[i][0] + py[i][0], zq[i][0]);
      v2f a1 = __builtin_elementwise_fma((v2f)lam_c, px[i][1] + py[i][1], zq[i][1]);
      a0 = __builtin_elementwise_fma(nlmdx[0], pxs0, a0);
      a1 = __builtin_elementwise_fma(nlmdx[1], pxs1, a1);
      a0 = __builtin_elementwise_fma((v2f)nlmy[i], pyu0, a0);
      a1 = __builtin_elementwise_fma((v2f)nlmy[i], pyu1, a1);
      u[i][0] = __builtin_elementwise_max(a0, a0 * ALPHA);
      u[i][1] = __builtin_elementwise_max(a1, a1 * ALPHA);
    }
    *reinterpret_cast<float4*>(&su_r0[sur0_w]) =
        make_float4(u[0][0].x, u[0][0].y, u[0][1].x, u[0][1].y);
#pragma unroll
    for (int i = 0; i < 4; ++i) su_c0[suc0_w + i * 22] = u[i][0].x;
    __syncthreads();
  }

  // ---- write center 64x64 tile straight from registers ----
  if (act) {
#pragma unroll
    for (int i = 0; i < 4; ++i) {
      const int rr = r + i;                       // region row
      if (rr >= HALO && rr < HALO + TILE) {
        float* dst = out + base + (long)(r0 + rr) * W + gj;
        if (qc >= 3 && qc <= 17) {                // quad fully inside cols 10..73
          *reinterpret_cast<float4*>(dst) =
              make_float4(u[i][0].x, u[i][0].y, u[i][1].x, u[i][1].y);
        } else if (qc == 2 || qc == 18) {         // partial edge quads
          const float uv[4] = {u[i][0].x, u[i][0].y, u[i][1].x, u[i][1].y};
#pragma unroll
          for (int k = 0; k < 4; ++k) {
            const int cc = qc * 4 + k;            // region col
            if (cc >= HALO && cc < HALO + TILE) dst[k] = uv[k];
          }
        }
      }
    }
  }
}

} // namespace

extern "C" void kernel_launch(void* const* d_in, const int* in_sizes, int n_in,
                              void* d_out, int out_size, void* d_ws, size_t ws_size,
                              hipStream_t stream) {
  const float* z   = (const float*)d_in[0];
  const float* lam = (const float*)d_in[1];
  float* out = (float*)d_out;

  const int n_img = in_sizes[0] / (H * W);    // 512 for (8,64,256,256)
  const int n_blocks = n_img * 16;            // 4x4 tiles per image

  tv_lrelu_kernel<<<n_blocks, NT, 0, stream>>>(z, lam, out);
}